// Round 5
// baseline (7000.316 us; speedup 1.0000x reference)
//
#include <hip/hip_runtime.h>
#include <stdint.h>

typedef unsigned short u16;
typedef __bf16 bf16x8 __attribute__((ext_vector_type(8)));

#define ST 2048
#define SD 512

__device__ __forceinline__ u16 f2bf(float f) {
  union { float f; uint32_t u; } v; v.f = f;
  uint32_t r = v.u + 0x7FFFu + ((v.u >> 16) & 1u);
  return (u16)(r >> 16);
}
__device__ __forceinline__ float bf2f(u16 h) {
  union { uint32_t u; float f; } v; v.u = ((uint32_t)h) << 16; return v.f;
}
__device__ __forceinline__ bf16x8 ld8(const u16* p) {
  return *reinterpret_cast<const bf16x8*>(p);
}

// ---- Naive QKV projection, pure vector f32. Block: 512 threads = 8 rows x 512 cols.
// z=0 -> q as f32 (staged in d_out), z=1 -> k bf16, z=2 -> v bf16 transposed vt[b][d][t]
__global__ __launch_bounds__(512) void qkv_naive(
    const float* __restrict__ x0, const float* __restrict__ x1,
    const float* __restrict__ wq, const float* __restrict__ wk,
    const float* __restrict__ wv,
    float* __restrict__ q, u16* __restrict__ kk, u16* __restrict__ vt) {
  __shared__ float xr[8][1024];
  int z = blockIdx.y;
  const float* w = (z == 0) ? wq : (z == 1) ? wk : wv;
  int m0 = blockIdx.x * 8;
  int tid = threadIdx.x;
  for (int idx = tid; idx < 8 * 1024; idx += 512) {
    int r = idx >> 10, k = idx & 1023;
    int m = m0 + r;
    xr[r][k] = (k < SD) ? x0[(size_t)m * SD + k] : x1[(size_t)m * SD + (k - SD)];
  }
  __syncthreads();
  int n = tid;
  float acc[8] = {0.f, 0.f, 0.f, 0.f, 0.f, 0.f, 0.f, 0.f};
#pragma unroll 4
  for (int k = 0; k < 1024; ++k) {
    float wkn = w[(size_t)k * SD + n];
#pragma unroll
    for (int r = 0; r < 8; ++r) acc[r] += xr[r][k] * wkn;
  }
#pragma unroll
  for (int r = 0; r < 8; ++r) {
    int m = m0 + r;
    if (z == 0) q[(size_t)m * SD + n] = acc[r];
    else if (z == 1) kk[(size_t)m * SD + n] = f2bf(acc[r]);
    else {
      int b = m >> 11, t = m & 2047;
      vt[((size_t)b * SD + n) * ST + t] = f2bf(acc[r]);
    }
  }
}

// ---- block reductions (256 threads = 4 waves)
__device__ __forceinline__ float blk_max(float v, volatile float* red, int tid) {
#pragma unroll
  for (int o = 1; o < 64; o <<= 1) v = fmaxf(v, __shfl_xor(v, o));
  __syncthreads();
  if ((tid & 63) == 0) red[tid >> 6] = v;
  __syncthreads();
  return fmaxf(fmaxf(red[0], red[1]), fmaxf(red[2], red[3]));
}
__device__ __forceinline__ float blk_sum(float v, volatile float* red, int tid) {
#pragma unroll
  for (int o = 1; o < 64; o <<= 1) v += __shfl_xor(v, o);
  __syncthreads();
  if ((tid & 63) == 0) red[tid >> 6] = v;
  __syncthreads();
  return red[0] + red[1] + red[2] + red[3];
}

// ---- Naive causal attention + LayerNorm. One 256-thread block per (b,t) row.
// q (f32) lives in d_out; each block reads only the row it later overwrites.
__global__ __launch_bounds__(256) void attn_naive(
    const float* __restrict__ q, const u16* __restrict__ kk,
    const u16* __restrict__ vt, const float* __restrict__ gamma,
    const float* __restrict__ beta, float* __restrict__ out) {
  __shared__ float qrow[512];
  __shared__ float sc[2048];
  __shared__ float red[4];
  int t = blockIdx.x, b = blockIdx.y;
  int tid = threadIdx.x;
  const float scale = 0.044194173824159216f;  // 512^-0.5

  const float* qp = q + ((size_t)b * ST + t) * SD;
  for (int d = tid; d < SD; d += 256) qrow[d] = qp[d];
  __syncthreads();

  for (int s = tid; s <= t; s += 256) {
    const u16* kp = kk + ((size_t)b * ST + s) * SD;
    float a = 0.f;
    for (int d = 0; d < SD; d += 8) {
      bf16x8 kv = ld8(kp + d);
#pragma unroll
      for (int j = 0; j < 8; ++j) a += qrow[d + j] * (float)kv[j];
    }
    sc[s] = a * scale;
  }
  __syncthreads();

  float lmx = -1e30f;
  for (int s = tid; s <= t; s += 256) lmx = fmaxf(lmx, sc[s]);
  float mx = blk_max(lmx, red, tid);

  float lsum = 0.f;
  for (int s = tid; s <= t; s += 256) {
    float p = __expf(sc[s] - mx);
    sc[s] = p;
    lsum += p;
  }
  __syncthreads();
  float tot = blk_sum(lsum, red, tid);
  float invl = 1.0f / tot;

  const u16* v0p = vt + ((size_t)b * SD + tid) * ST;
  const u16* v1p = v0p + (size_t)256 * ST;
  float o0 = 0.f, o1 = 0.f;
  int smax8 = (t + 1) & ~7;
  for (int s = 0; s < smax8; s += 8) {
    bf16x8 va = ld8(v0p + s);
    bf16x8 vb8 = ld8(v1p + s);
#pragma unroll
    for (int j = 0; j < 8; ++j) {
      float p = sc[s + j];
      o0 += p * (float)va[j];
      o1 += p * (float)vb8[j];
    }
  }
  for (int s = smax8; s <= t; ++s) {
    float p = sc[s];
    o0 += p * bf2f(v0p[s]);
    o1 += p * bf2f(v1p[s]);
  }
  o0 *= invl; o1 *= invl;

  float s1 = blk_sum(o0 + o1, red, tid);
  float s2 = blk_sum(o0 * o0 + o1 * o1, red, tid);
  float mu = s1 * (1.f / 512.f);
  float var = s2 * (1.f / 512.f) - mu * mu;
  float rstd = rsqrtf(var + 1e-5f);

  float g0 = gamma[tid], g1 = gamma[tid + 256];
  float b0 = beta[tid], b1 = beta[tid + 256];
  __syncthreads();  // all reads of q-row done before overwrite
  float* orow = out + ((size_t)b * ST + t) * SD;
  orow[tid]       = (o0 - mu) * rstd * g0 + b0;
  orow[tid + 256] = (o1 - mu) * rstd * g1 + b1;
}

extern "C" void kernel_launch(void* const* d_in, const int* in_sizes, int n_in,
                              void* d_out, int out_size, void* d_ws, size_t ws_size,
                              hipStream_t stream) {
  (void)in_sizes; (void)n_in; (void)out_size; (void)ws_size;
  const float* x0 = (const float*)d_in[0];
  const float* x1 = (const float*)d_in[1];
  const float* Wq = (const float*)d_in[2];
  const float* Wk = (const float*)d_in[3];
  const float* Wv = (const float*)d_in[4];
  const float* gamma = (const float*)d_in[5];
  const float* beta = (const float*)d_in[6];
  u16* ws = (u16*)d_ws;
  u16* kk = ws;                                // 16384*512 u16 = 16.78 MB
  u16* vt = kk + (size_t)16384 * 512;          // 8*512*2048 u16 = 16.78 MB
  float* q = (float*)d_out;                    // q staged as f32 in d_out (exact fit)
  float* out = (float*)d_out;

  qkv_naive<<<dim3(2048, 3), dim3(512), 0, stream>>>(x0, x1, Wq, Wk, Wv, q, kk, vt);
  attn_naive<<<dim3(2048, 8), dim3(256), 0, stream>>>(q, kk, vt, gamma, beta, out);
}

// Round 6
// 1420.960 us; speedup vs baseline: 4.9265x; 4.9265x over previous
//
#include <hip/hip_runtime.h>
#include <stdint.h>

typedef unsigned short u16;
typedef float floatx4 __attribute__((ext_vector_type(4)));
typedef __bf16 bf16x4 __attribute__((ext_vector_type(4)));
typedef __bf16 bf16x8 __attribute__((ext_vector_type(8)));

#define ST 2048
#define SD 512

__device__ __forceinline__ floatx4 mfma16(bf16x8 a, bf16x8 b, floatx4 c) {
  return __builtin_amdgcn_mfma_f32_16x16x32_bf16(a, b, c, 0, 0, 0);
}
__device__ __forceinline__ bf16x8 ld8(const u16* p) {
  return *reinterpret_cast<const bf16x8*>(p);
}
__device__ __forceinline__ u16 f2bf(float f) {
  union { float f; uint32_t u; } v; v.f = f;
  uint32_t r = v.u + 0x7FFFu + ((v.u >> 16) & 1u);
  return (u16)(r >> 16);
}
__device__ __forceinline__ bf16x8 cvt2bf8(floatx4 a, floatx4 b) {
  bf16x4 lo = __builtin_convertvector(a, bf16x4);
  bf16x4 hi = __builtin_convertvector(b, bf16x4);
  bf16x8 r;
  r[0] = lo[0]; r[1] = lo[1]; r[2] = lo[2]; r[3] = lo[3];
  r[4] = hi[0]; r[5] = hi[1]; r[6] = hi[2]; r[7] = hi[3];
  return r;
}

// ---- W transpose+cast: f32 [1024,512] -> bf16 [512,1024] x3
__global__ void wtrans(const float* __restrict__ wq, const float* __restrict__ wk,
                       const float* __restrict__ wv, u16* __restrict__ wt) {
  __shared__ float tile[32][33];
  const float* w = (blockIdx.z == 0) ? wq : (blockIdx.z == 1) ? wk : wv;
  u16* o = wt + (size_t)blockIdx.z * (SD * 1024);
  int k0 = blockIdx.x * 32, n0 = blockIdx.y * 32;
  int tx = threadIdx.x, ty = threadIdx.y;
#pragma unroll
  for (int i = 0; i < 32; i += 8)
    tile[ty + i][tx] = w[(size_t)(k0 + ty + i) * SD + n0 + tx];
  __syncthreads();
#pragma unroll
  for (int i = 0; i < 32; i += 8)
    o[(size_t)(n0 + ty + i) * 1024 + k0 + tx] = f2bf(tile[tx][ty + i]);
}

// ---- QKV projection: Y = concat(x0,x1) @ W. 64x64 tile per 4-wave workgroup.
// z=0 -> q bf16 [m][d], z=1 -> k bf16 [m][d], z=2 -> v bf16 TRANSPOSED vt[b][d][t]
__global__ void qkv_gemm(const float* __restrict__ x0, const float* __restrict__ x1,
                         const u16* __restrict__ wt,
                         u16* __restrict__ qb, u16* __restrict__ kk,
                         u16* __restrict__ vt) {
  int tid = threadIdx.x;
  int wave = tid >> 6, lane = tid & 63;
  int quad = lane >> 4, l16 = lane & 15;
  int mw = blockIdx.x * 64 + wave * 16;
  int n0 = blockIdx.y * 64;
  int z = blockIdx.z;
  const u16* wz = wt + (size_t)z * (SD * 1024);
  floatx4 zero = {0.f, 0.f, 0.f, 0.f};
  floatx4 acc[4];
#pragma unroll
  for (int i = 0; i < 4; ++i) acc[i] = zero;
  int row = mw + l16;
  const float* xr0 = x0 + (size_t)row * SD;
  const float* xr1 = x1 + (size_t)row * SD;
#pragma unroll 2
  for (int k0 = 0; k0 < 1024; k0 += 32) {
    int ko = k0 + quad * 8;  // 8-chunk never straddles the 512 boundary
    const float* src = (ko < SD) ? (xr0 + ko) : (xr1 + (ko - SD));
    floatx4 f0 = *reinterpret_cast<const floatx4*>(src);
    floatx4 f1 = *reinterpret_cast<const floatx4*>(src + 4);
    bf16x8 a = cvt2bf8(f0, f1);
#pragma unroll
    for (int nt = 0; nt < 4; ++nt) {
      bf16x8 b = ld8(wz + (size_t)(n0 + nt * 16 + l16) * 1024 + ko);
      acc[nt] = mfma16(a, b, acc[nt]);
    }
  }
  int rbase = mw + quad * 4;  // C/D: row = quad*4+reg, col = lane&15
#pragma unroll
  for (int nt = 0; nt < 4; ++nt) {
    int col = n0 + nt * 16 + l16;
#pragma unroll
    for (int r = 0; r < 4; ++r) {
      int m = rbase + r;
      u16 h = f2bf(acc[nt][r]);
      if (z == 0) qb[(size_t)m * SD + col] = h;
      else if (z == 1) kk[(size_t)m * SD + col] = h;
      else {
        int bb = m >> 11, t = m & 2047;
        vt[((size_t)bb * SD + col) * ST + t] = h;
      }
    }
  }
}

// ---- Flash attention (causal) + fused LayerNorm. One wave owns 16 Q-rows x D=512.
__global__ __launch_bounds__(64, 2) void attn(
    const u16* __restrict__ qb, const u16* __restrict__ kk,
    const u16* __restrict__ vt, const float* __restrict__ gamma,
    const float* __restrict__ beta, float* __restrict__ out) {
  __shared__ u16 plds[16 * 72];  // P round-trip, stride 72 elems (144B)
  int lane = threadIdx.x & 63;
  int quad = lane >> 4, l16 = lane & 15;
  int b = blockIdx.x >> 7;
  int it = 127 - (blockIdx.x & 127);  // heavy tiles first
  int t0 = it * 16;
  int smax = t0 + 15;
  const float scale = 0.044194173824159216f;  // 512^-0.5

  const u16* qp = qb + (size_t)(b * ST + t0 + l16) * SD;
  bf16x8 qf[16];
#pragma unroll
  for (int c = 0; c < 16; ++c) qf[c] = ld8(qp + c * 32 + quad * 8);

  floatx4 zero = {0.f, 0.f, 0.f, 0.f};
  floatx4 acc[32];
#pragma unroll
  for (int i = 0; i < 32; ++i) acc[i] = zero;
  float mrow[4] = {-1e30f, -1e30f, -1e30f, -1e30f};
  float lrow[4] = {0.f, 0.f, 0.f, 0.f};

  const u16* kb0 = kk + (size_t)b * ST * SD;
  const u16* vb0 = vt + (size_t)b * SD * ST;

  for (int s0 = 0; s0 <= smax; s0 += 64) {
    int rem = smax - s0;
    int ntmax = rem >> 4; if (ntmax > 3) ntmax = 3;
    int cmax = rem >> 5;  if (cmax > 1) cmax = 1;
    bool diag = (s0 + 63) > t0;
    floatx4 sacc[4];
#pragma unroll
    for (int nt = 0; nt < 4; ++nt) {
      if (nt <= ntmax) {
        sacc[nt] = zero;
        const u16* kb = kb0 + (size_t)(s0 + nt * 16 + l16) * SD;
#pragma unroll
        for (int c = 0; c < 16; ++c)
          sacc[nt] = mfma16(qf[c], ld8(kb + c * 32 + quad * 8), sacc[nt]);
#pragma unroll
        for (int r = 0; r < 4; ++r) {
          float sv = sacc[nt][r] * scale;
          if (diag) {
            int sg = s0 + nt * 16 + l16;
            int tg = t0 + quad * 4 + r;
            sv = (sg > tg) ? -1e30f : sv;
          }
          sacc[nt][r] = sv;
        }
      } else {
        floatx4 neg = {-1e30f, -1e30f, -1e30f, -1e30f};
        sacc[nt] = neg;
      }
    }
    // online softmax: row lives in the quad's 16 lanes at reg r
    float mnew[4], alpha[4];
#pragma unroll
    for (int r = 0; r < 4; ++r) {
      float mx = fmaxf(fmaxf(sacc[0][r], sacc[1][r]), fmaxf(sacc[2][r], sacc[3][r]));
      mx = fmaxf(mx, __shfl_xor(mx, 1));
      mx = fmaxf(mx, __shfl_xor(mx, 2));
      mx = fmaxf(mx, __shfl_xor(mx, 4));
      mx = fmaxf(mx, __shfl_xor(mx, 8));
      float mn = fmaxf(mrow[r], mx);
      alpha[r] = __expf(mrow[r] - mn);
      mnew[r] = mn;
      mrow[r] = mn;
    }
#pragma unroll
    for (int r = 0; r < 4; ++r) {
      float rs = 0.f;
#pragma unroll
      for (int nt = 0; nt < 4; ++nt) {
        float p = __expf(sacc[nt][r] - mnew[r]);  // masked -> exactly 0
        rs += p;
        plds[(quad * 4 + r) * 72 + nt * 16 + l16] = f2bf(p);
      }
      rs += __shfl_xor(rs, 1);
      rs += __shfl_xor(rs, 2);
      rs += __shfl_xor(rs, 4);
      rs += __shfl_xor(rs, 8);
      lrow[r] = lrow[r] * alpha[r] + rs;
    }
#pragma unroll
    for (int nt = 0; nt < 32; ++nt) {
#pragma unroll
      for (int r = 0; r < 4; ++r) acc[nt][r] *= alpha[r];
    }
    __syncthreads();  // P C-layout writes -> A-layout reads
#pragma unroll
    for (int c = 0; c < 2; ++c) {
      if (c <= cmax) {
        bf16x8 pf = ld8(&plds[l16 * 72 + c * 32 + quad * 8]);
        const u16* vb = vb0 + s0 + c * 32 + quad * 8;
#pragma unroll
        for (int nt = 0; nt < 32; ++nt) {
          bf16x8 vf = ld8(vb + (size_t)(nt * 16 + l16) * ST);
          acc[nt] = mfma16(pf, vf, acc[nt]);
        }
      }
    }
    __syncthreads();  // reads done before next step's writes
  }

  // epilogue: O = acc/l, LayerNorm over D=512, write f32
#pragma unroll
  for (int r = 0; r < 4; ++r) {
    float invl = 1.0f / lrow[r];
    float s1 = 0.f, s2 = 0.f;
#pragma unroll
    for (int nt = 0; nt < 32; ++nt) {
      float o = acc[nt][r] * invl;
      s1 += o;
      s2 += o * o;
    }
    s1 += __shfl_xor(s1, 1); s1 += __shfl_xor(s1, 2);
    s1 += __shfl_xor(s1, 4); s1 += __shfl_xor(s1, 8);
    s2 += __shfl_xor(s2, 1); s2 += __shfl_xor(s2, 2);
    s2 += __shfl_xor(s2, 4); s2 += __shfl_xor(s2, 8);
    float mu = s1 * (1.f / 512.f);
    float var = s2 * (1.f / 512.f) - mu * mu;
    float rstd = rsqrtf(var + 1e-5f);
    int t = t0 + quad * 4 + r;
    float* orow = out + (size_t)(b * ST + t) * SD;
#pragma unroll
    for (int nt = 0; nt < 32; ++nt) {
      int col = nt * 16 + l16;
      float g = gamma[col];
      float be = beta[col];
      orow[col] = (acc[nt][r] * invl - mu) * rstd * g + be;
    }
  }
}

extern "C" void kernel_launch(void* const* d_in, const int* in_sizes, int n_in,
                              void* d_out, int out_size, void* d_ws, size_t ws_size,
                              hipStream_t stream) {
  (void)in_sizes; (void)n_in; (void)out_size; (void)ws_size;
  const float* x0 = (const float*)d_in[0];
  const float* x1 = (const float*)d_in[1];
  const float* Wq = (const float*)d_in[2];
  const float* Wk = (const float*)d_in[3];
  const float* Wv = (const float*)d_in[4];
  const float* gamma = (const float*)d_in[5];
  const float* beta = (const float*)d_in[6];
  u16* ws = (u16*)d_ws;
  u16* wt = ws;                                // 3*512*1024  ( 3.1 MB)
  u16* qb = wt + (size_t)3 * 512 * 1024;       // 16384*512   (16.8 MB)
  u16* kk = qb + (size_t)16384 * 512;          // 16384*512   (16.8 MB)
  u16* vt = kk + (size_t)16384 * 512;          // 8*512*2048  (16.8 MB)
  float* out = (float*)d_out;

  wtrans<<<dim3(32, 16, 3), dim3(32, 8), 0, stream>>>(Wq, Wk, Wv, wt);
  qkv_gemm<<<dim3(256, 8, 3), dim3(256), 0, stream>>>(x0, x1, wt, qb, kk, vt);
  attn<<<dim3(1024), dim3(64), 0, stream>>>(qb, kk, vt, gamma, beta, out);
}

// Round 7
// 846.969 us; speedup vs baseline: 8.2651x; 1.6777x over previous
//
#include <hip/hip_runtime.h>
#include <stdint.h>

typedef unsigned short u16;
typedef float floatx4 __attribute__((ext_vector_type(4)));
typedef __bf16 bf16x4 __attribute__((ext_vector_type(4)));
typedef __bf16 bf16x8 __attribute__((ext_vector_type(8)));

#define ST 2048
#define SD 512

__device__ __forceinline__ floatx4 mfma16(bf16x8 a, bf16x8 b, floatx4 c) {
  return __builtin_amdgcn_mfma_f32_16x16x32_bf16(a, b, c, 0, 0, 0);
}
__device__ __forceinline__ bf16x8 ld8(const u16* p) {
  return *reinterpret_cast<const bf16x8*>(p);
}
__device__ __forceinline__ u16 f2bf(float f) {
  union { float f; uint32_t u; } v; v.f = f;
  uint32_t r = v.u + 0x7FFFu + ((v.u >> 16) & 1u);
  return (u16)(r >> 16);
}
__device__ __forceinline__ bf16x8 cvt2bf8(floatx4 a, floatx4 b) {
  bf16x4 lo = __builtin_convertvector(a, bf16x4);
  bf16x4 hi = __builtin_convertvector(b, bf16x4);
  bf16x8 r;
  r[0] = lo[0]; r[1] = lo[1]; r[2] = lo[2]; r[3] = lo[3];
  r[4] = hi[0]; r[5] = hi[1]; r[6] = hi[2]; r[7] = hi[3];
  return r;
}

// ---- x concat + cast: xc[m][k] bf16, k<512 from x0 else x1. 8 elems/thread.
__global__ __launch_bounds__(256) void xcast(const float* __restrict__ x0,
                                             const float* __restrict__ x1,
                                             u16* __restrict__ xc) {
  size_t f = ((size_t)blockIdx.x * 256 + threadIdx.x) * 8;  // flat elem idx
  int m = (int)(f >> 10), k = (int)(f & 1023);
  const float* src = (k < SD) ? (x0 + (size_t)m * SD + k)
                              : (x1 + (size_t)m * SD + (k - SD));
  floatx4 a = *reinterpret_cast<const floatx4*>(src);
  floatx4 b = *reinterpret_cast<const floatx4*>(src + 4);
  *reinterpret_cast<bf16x8*>(xc + f) = cvt2bf8(a, b);
}

// ---- W transpose+cast: f32 [1024,512] -> bf16 [512,1024] x3
__global__ void wtrans(const float* __restrict__ wq, const float* __restrict__ wk,
                       const float* __restrict__ wv, u16* __restrict__ wt) {
  __shared__ float tile[32][33];
  const float* w = (blockIdx.z == 0) ? wq : (blockIdx.z == 1) ? wk : wv;
  u16* o = wt + (size_t)blockIdx.z * (SD * 1024);
  int k0 = blockIdx.x * 32, n0 = blockIdx.y * 32;
  int tx = threadIdx.x, ty = threadIdx.y;
#pragma unroll
  for (int i = 0; i < 32; i += 8)
    tile[ty + i][tx] = w[(size_t)(k0 + ty + i) * SD + n0 + tx];
  __syncthreads();
#pragma unroll
  for (int i = 0; i < 32; i += 8)
    o[(size_t)(n0 + ty + i) * 1024 + k0 + tx] = f2bf(tile[tx][ty + i]);
}

// ---- Fused QKV: one block computes q,k,v for a 64(m)x64(n) tile. A reused x3.
__global__ __launch_bounds__(256) void qkv_fused(
    const u16* __restrict__ xc, const u16* __restrict__ wt,
    u16* __restrict__ qb, u16* __restrict__ kk, u16* __restrict__ vt) {
  int tid = threadIdx.x;
  int wave = tid >> 6, lane = tid & 63;
  int quad = lane >> 4, l16 = lane & 15;
  int mw = blockIdx.x * 64 + wave * 16;
  int n0 = blockIdx.y * 64;
  floatx4 zero = {0.f, 0.f, 0.f, 0.f};
  floatx4 acc[3][4];
#pragma unroll
  for (int z = 0; z < 3; ++z)
#pragma unroll
    for (int i = 0; i < 4; ++i) acc[z][i] = zero;
  const u16* xr = xc + (size_t)(mw + l16) * 1024 + quad * 8;
#pragma unroll 2
  for (int k0 = 0; k0 < 1024; k0 += 32) {
    bf16x8 a = ld8(xr + k0);
#pragma unroll
    for (int z = 0; z < 3; ++z) {
      const u16* wz = wt + (size_t)z * (SD * 1024) + k0 + quad * 8;
#pragma unroll
      for (int nt = 0; nt < 4; ++nt) {
        bf16x8 b = ld8(wz + (size_t)(n0 + nt * 16 + l16) * 1024);
        acc[z][nt] = mfma16(a, b, acc[z][nt]);
      }
    }
  }
  int rbase = mw + quad * 4;  // C/D: row = quad*4+reg, col = lane&15
#pragma unroll
  for (int z = 0; z < 3; ++z) {
#pragma unroll
    for (int nt = 0; nt < 4; ++nt) {
      int col = n0 + nt * 16 + l16;
#pragma unroll
      for (int r = 0; r < 4; ++r) {
        int m = rbase + r;
        u16 h = f2bf(acc[z][nt][r]);
        if (z == 0) qb[(size_t)m * SD + col] = h;
        else if (z == 1) kk[(size_t)m * SD + col] = h;
        else {
          int bb = m >> 11, t = m & 2047;
          vt[((size_t)bb * SD + col) * ST + t] = h;
        }
      }
    }
  }
}

// ---- Flash attention (causal) + fused LayerNorm.
// 4 waves/block split the s-range of one 16-row Q-tile; block does 2 tiles
// (pair it, 127-it -> uniform work). b = blockIdx&7 for XCD/L2 locality.
__global__ __launch_bounds__(256, 2) void attn2(
    const u16* __restrict__ qb, const u16* __restrict__ kk,
    const u16* __restrict__ vt, const float* __restrict__ gamma,
    const float* __restrict__ beta, float* __restrict__ out) {
  __shared__ u16 plds[4][16 * 72];
  __shared__ float obuf[16 * 512];
  __shared__ float mst[4][16];
  __shared__ float lst[4][16];
  int tid = threadIdx.x;
  int wave = tid >> 6, lane = tid & 63;
  int quad = lane >> 4, l16 = lane & 15;
  int b = blockIdx.x & 7;
  int pr = blockIdx.x >> 3;  // 0..63
  const float scale = 0.044194173824159216f;  // 512^-0.5
  const u16* kb0 = kk + (size_t)b * ST * SD;
  const u16* vb0 = vt + (size_t)b * SD * ST;
  u16* myp = &plds[wave][0];

#pragma unroll 1
  for (int half = 0; half < 2; ++half) {
    int it = half ? pr : (127 - pr);
    int t0 = it * 16;
    int smax = t0 + 15;
    const u16* qp = qb + (size_t)(b * ST + t0 + l16) * SD + quad * 8;

    floatx4 zero = {0.f, 0.f, 0.f, 0.f};
    floatx4 acc[32];
#pragma unroll
    for (int i = 0; i < 32; ++i) acc[i] = zero;
    float mrow[4] = {-1e30f, -1e30f, -1e30f, -1e30f};
    float lrow[4] = {0.f, 0.f, 0.f, 0.f};

#pragma unroll 1
    for (int s0 = wave * 64; s0 <= smax; s0 += 256) {
      int rem = smax - s0;
      int ntmax = rem >> 4; if (ntmax > 3) ntmax = 3;
      int cmax = rem >> 5;  if (cmax > 1) cmax = 1;
      bool diag = (s0 + 63) > t0;
      floatx4 sacc[4];
#pragma unroll
      for (int nt = 0; nt < 4; ++nt) sacc[nt] = zero;
      // QK^T: A-frag (q) reloaded per chain step (L1-broadcast across waves)
#pragma unroll
      for (int c = 0; c < 16; ++c) {
        bf16x8 a = ld8(qp + c * 32);
        const u16* kb = kb0 + (size_t)(s0 + l16) * SD + c * 32 + quad * 8;
#pragma unroll
        for (int nt = 0; nt < 4; ++nt) {
          if (nt <= ntmax)
            sacc[nt] = mfma16(a, ld8(kb + (size_t)nt * 16 * SD), sacc[nt]);
        }
      }
#pragma unroll
      for (int nt = 0; nt < 4; ++nt) {
        if (nt <= ntmax) {
#pragma unroll
          for (int r = 0; r < 4; ++r) {
            float sv = sacc[nt][r] * scale;
            if (diag) {
              int sg = s0 + nt * 16 + l16;
              int tg = t0 + quad * 4 + r;
              sv = (sg > tg) ? -1e30f : sv;
            }
            sacc[nt][r] = sv;
          }
        } else {
          floatx4 neg = {-1e30f, -1e30f, -1e30f, -1e30f};
          sacc[nt] = neg;
        }
      }
      // online softmax (rows live in quad's 16 lanes at reg r)
      float mnew[4], alpha[4];
#pragma unroll
      for (int r = 0; r < 4; ++r) {
        float mx = fmaxf(fmaxf(sacc[0][r], sacc[1][r]), fmaxf(sacc[2][r], sacc[3][r]));
        mx = fmaxf(mx, __shfl_xor(mx, 1));
        mx = fmaxf(mx, __shfl_xor(mx, 2));
        mx = fmaxf(mx, __shfl_xor(mx, 4));
        mx = fmaxf(mx, __shfl_xor(mx, 8));
        float mn = fmaxf(mrow[r], mx);
        alpha[r] = __expf(mrow[r] - mn);
        mnew[r] = mn;
        mrow[r] = mn;
      }
#pragma unroll
      for (int r = 0; r < 4; ++r) {
        float rs = 0.f;
#pragma unroll
        for (int nt = 0; nt < 4; ++nt) {
          float p = __expf(sacc[nt][r] - mnew[r]);  // masked -> exactly 0
          rs += p;
          myp[(quad * 4 + r) * 72 + nt * 16 + l16] = f2bf(p);
        }
        rs += __shfl_xor(rs, 1);
        rs += __shfl_xor(rs, 2);
        rs += __shfl_xor(rs, 4);
        rs += __shfl_xor(rs, 8);
        lrow[r] = lrow[r] * alpha[r] + rs;
      }
#pragma unroll
      for (int nt = 0; nt < 32; ++nt) {
#pragma unroll
        for (int r = 0; r < 4; ++r) acc[nt][r] *= alpha[r];
      }
      // PV: per-wave private plds slice -> NO barrier needed
#pragma unroll
      for (int c = 0; c < 2; ++c) {
        if (c <= cmax) {
          bf16x8 pf = ld8(myp + l16 * 72 + c * 32 + quad * 8);
          const u16* vb = vb0 + (size_t)l16 * ST + s0 + c * 32 + quad * 8;
#pragma unroll
          for (int nt = 0; nt < 32; ++nt) {
            bf16x8 vf = ld8(vb + (size_t)nt * 16 * ST);
            acc[nt] = mfma16(pf, vf, acc[nt]);
          }
        }
      }
    }

    // ---- cross-wave merge of (m, l, acc)
    if (l16 == 0) {
#pragma unroll
      for (int r = 0; r < 4; ++r) {
        mst[wave][quad * 4 + r] = mrow[r];
        lst[wave][quad * 4 + r] = lrow[r];
      }
    }
    __syncthreads();
    float wsc[4];
#pragma unroll
    for (int r = 0; r < 4; ++r) {
      int row = quad * 4 + r;
      float mg = fmaxf(fmaxf(mst[0][row], mst[1][row]),
                       fmaxf(mst[2][row], mst[3][row]));
      wsc[r] = __expf(mrow[r] - mg);
    }
#pragma unroll 1
    for (int w = 0; w < 4; ++w) {
      if (wave == w) {
#pragma unroll
        for (int nt = 0; nt < 32; ++nt) {
#pragma unroll
          for (int r = 0; r < 4; ++r) {
            int idx = (quad * 4 + r) * 512 + nt * 16 + l16;
            float v = wsc[r] * acc[nt][r];
            if (w == 0) obuf[idx] = v;
            else obuf[idx] += v;
          }
        }
      }
      __syncthreads();
    }

    // ---- epilogue: wave handles rows wave*4..wave*4+3; LN over 512; f32 out
#pragma unroll
    for (int rr = 0; rr < 4; ++rr) {
      int row = wave * 4 + rr;
      float mgr = fmaxf(fmaxf(mst[0][row], mst[1][row]),
                        fmaxf(mst[2][row], mst[3][row]));
      float lg = __expf(mst[0][row] - mgr) * lst[0][row] +
                 __expf(mst[1][row] - mgr) * lst[1][row] +
                 __expf(mst[2][row] - mgr) * lst[2][row] +
                 __expf(mst[3][row] - mgr) * lst[3][row];
      float invl = 1.0f / lg;
      const float* op = &obuf[row * 512 + lane * 8];
      floatx4 o0 = *reinterpret_cast<const floatx4*>(op);
      floatx4 o1 = *reinterpret_cast<const floatx4*>(op + 4);
      float s1 = 0.f, s2 = 0.f;
#pragma unroll
      for (int j = 0; j < 4; ++j) {
        o0[j] *= invl; o1[j] *= invl;
        s1 += o0[j] + o1[j];
        s2 += o0[j] * o0[j] + o1[j] * o1[j];
      }
#pragma unroll
      for (int o = 1; o < 64; o <<= 1) {
        s1 += __shfl_xor(s1, o);
        s2 += __shfl_xor(s2, o);
      }
      float mu = s1 * (1.f / 512.f);
      float var = s2 * (1.f / 512.f) - mu * mu;
      float rstd = rsqrtf(var + 1e-5f);
      const float* gp = gamma + lane * 8;
      const float* bp = beta + lane * 8;
      floatx4 g0 = *reinterpret_cast<const floatx4*>(gp);
      floatx4 g1 = *reinterpret_cast<const floatx4*>(gp + 4);
      floatx4 be0 = *reinterpret_cast<const floatx4*>(bp);
      floatx4 be1 = *reinterpret_cast<const floatx4*>(bp + 4);
      floatx4 r0, r1;
#pragma unroll
      for (int j = 0; j < 4; ++j) {
        r0[j] = (o0[j] - mu) * rstd * g0[j] + be0[j];
        r1[j] = (o1[j] - mu) * rstd * g1[j] + be1[j];
      }
      float* orow = out + (size_t)(b * ST + t0 + row) * SD + lane * 8;
      *reinterpret_cast<floatx4*>(orow) = r0;
      *reinterpret_cast<floatx4*>(orow + 4) = r1;
    }
    __syncthreads();  // protect obuf/stats before next half reuses them
  }
}

extern "C" void kernel_launch(void* const* d_in, const int* in_sizes, int n_in,
                              void* d_out, int out_size, void* d_ws, size_t ws_size,
                              hipStream_t stream) {
  (void)in_sizes; (void)n_in; (void)out_size; (void)ws_size;
  const float* x0 = (const float*)d_in[0];
  const float* x1 = (const float*)d_in[1];
  const float* Wq = (const float*)d_in[2];
  const float* Wk = (const float*)d_in[3];
  const float* Wv = (const float*)d_in[4];
  const float* gamma = (const float*)d_in[5];
  const float* beta = (const float*)d_in[6];
  u16* ws = (u16*)d_ws;
  u16* wt = ws;                                // 3*512*1024   ( 3.1 MB)
  u16* qb = wt + (size_t)3 * 512 * 1024;       // 16384*512    (16.8 MB)
  u16* kk = qb + (size_t)16384 * 512;          // 16384*512    (16.8 MB)
  u16* vt = kk + (size_t)16384 * 512;          // 8*512*2048   (16.8 MB)
  u16* xc = vt + (size_t)8 * 512 * 2048;       // 16384*1024   (33.6 MB)
  float* out = (float*)d_out;

  xcast<<<dim3(8192), dim3(256), 0, stream>>>(x0, x1, xc);
  wtrans<<<dim3(32, 16, 3), dim3(32, 8), 0, stream>>>(Wq, Wk, Wv, wt);
  qkv_fused<<<dim3(256, 8), dim3(256), 0, stream>>>(xc, wt, qb, kk, vt);
  attn2<<<dim3(512), dim3(256), 0, stream>>>(qb, kk, vt, gamma, beta, out);
}

// Round 8
// 455.012 us; speedup vs baseline: 15.3849x; 1.8614x over previous
//
#include <hip/hip_runtime.h>
#include <stdint.h>

typedef unsigned short u16;
typedef float floatx4 __attribute__((ext_vector_type(4)));
typedef __bf16 bf16x4 __attribute__((ext_vector_type(4)));
typedef __bf16 bf16x8 __attribute__((ext_vector_type(8)));

#define ST 2048
#define SD 512

__device__ __forceinline__ floatx4 mfma16(bf16x8 a, bf16x8 b, floatx4 c) {
  return __builtin_amdgcn_mfma_f32_16x16x32_bf16(a, b, c, 0, 0, 0);
}
__device__ __forceinline__ bf16x8 ld8(const u16* p) {
  return *reinterpret_cast<const bf16x8*>(p);
}
__device__ __forceinline__ u16 f2bf(float f) {
  union { float f; uint32_t u; } v; v.f = f;
  uint32_t r = v.u + 0x7FFFu + ((v.u >> 16) & 1u);
  return (u16)(r >> 16);
}
__device__ __forceinline__ bf16x8 cvt2bf8(floatx4 a, floatx4 b) {
  bf16x4 lo = __builtin_convertvector(a, bf16x4);
  bf16x4 hi = __builtin_convertvector(b, bf16x4);
  bf16x8 r;
  r[0] = lo[0]; r[1] = lo[1]; r[2] = lo[2]; r[3] = lo[3];
  r[4] = hi[0]; r[5] = hi[1]; r[6] = hi[2]; r[7] = hi[3];
  return r;
}
// async global->LDS, 16 B per lane; LDS dst = wave-uniform base + lane*16
__device__ __forceinline__ void gl2lds(const u16* g, u16* l) {
  __builtin_amdgcn_global_load_lds(
      (const __attribute__((address_space(1))) unsigned int*)g,
      (__attribute__((address_space(3))) unsigned int*)l, 16, 0, 0);
}

// ---- x concat + cast: xc[m][k] bf16
__global__ __launch_bounds__(256) void xcast(const float* __restrict__ x0,
                                             const float* __restrict__ x1,
                                             u16* __restrict__ xc) {
  size_t f = ((size_t)blockIdx.x * 256 + threadIdx.x) * 8;
  int m = (int)(f >> 10), k = (int)(f & 1023);
  const float* src = (k < SD) ? (x0 + (size_t)m * SD + k)
                              : (x1 + (size_t)m * SD + (k - SD));
  floatx4 a = *reinterpret_cast<const floatx4*>(src);
  floatx4 b = *reinterpret_cast<const floatx4*>(src + 4);
  *reinterpret_cast<bf16x8*>(xc + f) = cvt2bf8(a, b);
}

// ---- W transpose+cast: f32 [1024,512] -> bf16 [512,1024] x3 (stacked rows 0..1535)
__global__ void wtrans(const float* __restrict__ wq, const float* __restrict__ wk,
                       const float* __restrict__ wv, u16* __restrict__ wt) {
  __shared__ float tile[32][33];
  const float* w = (blockIdx.z == 0) ? wq : (blockIdx.z == 1) ? wk : wv;
  u16* o = wt + (size_t)blockIdx.z * (SD * 1024);
  int k0 = blockIdx.x * 32, n0 = blockIdx.y * 32;
  int tx = threadIdx.x, ty = threadIdx.y;
#pragma unroll
  for (int i = 0; i < 32; i += 8)
    tile[ty + i][tx] = w[(size_t)(k0 + ty + i) * SD + n0 + tx];
  __syncthreads();
#pragma unroll
  for (int i = 0; i < 32; i += 8)
    o[(size_t)(n0 + ty + i) * 1024 + k0 + tx] = f2bf(tile[tx][ty + i]);
}

// ---- QKV as one m97-style GEMM: C[16384 x 1536] = xc[16384x1024] . wt[1536x1024]^T
// 128x128 tile, BK=32, global_load_lds staging, double-buffered 1-barrier K-loop.
__global__ __launch_bounds__(256, 2) void qkv_m97(
    const u16* __restrict__ xc, const u16* __restrict__ wt,
    u16* __restrict__ qb, u16* __restrict__ kk, u16* __restrict__ vt) {
  __shared__ __align__(16) u16 lA[2][128 * 32];
  __shared__ __align__(16) u16 lB[2][128 * 32];
  int tid = threadIdx.x;
  int wave = tid >> 6, lane = tid & 63;
  int quad = lane >> 4, l16 = lane & 15;
  int m0 = blockIdx.x * 128;
  int n0 = blockIdx.y * 128;
  int wm = (wave & 1) * 64, wn = (wave >> 1) * 64;
  int srow = lane >> 2, schunk = lane & 3;
  int fsw = (l16 >> 1) & 3;  // frag-read chunk swizzle (row>>1)&3, lane-only part

  floatx4 zero = {0.f, 0.f, 0.f, 0.f};
  floatx4 acc[4][4];
#pragma unroll
  for (int i = 0; i < 4; ++i)
#pragma unroll
    for (int j = 0; j < 4; ++j) acc[i][j] = zero;

  // stage k-chunk into buf: LDS slot (row, c) holds global chunk c ^ ((row>>1)&3)
#define QKV_STAGE(K0, BUF)                                                     \
  {                                                                            \
    _Pragma("unroll") for (int i = 0; i < 2; ++i) {                            \
      int r0 = (i * 4 + wave) * 16;                                            \
      int ra = r0 + srow;                                                      \
      int gc = schunk ^ ((srow >> 1) & 3);                                     \
      gl2lds(xc + (size_t)(m0 + ra) * 1024 + (K0) + gc * 8, &lA[BUF][r0 * 32]);\
      gl2lds(wt + (size_t)(n0 + ra) * 1024 + (K0) + gc * 8, &lB[BUF][r0 * 32]);\
    }                                                                          \
  }

  QKV_STAGE(0, 0);
#pragma unroll 1
  for (int it = 0; it < 32; ++it) {
    __syncthreads();  // drains prefetch of chunk `it`; frees buffer (it+1)&1
    if (it + 1 < 32) QKV_STAGE((it + 1) * 32, (it + 1) & 1);
    int buf = it & 1;
    bf16x8 fa[4], fb[4];
#pragma unroll
    for (int t = 0; t < 4; ++t) {
      int ra = wm + t * 16 + l16;
      fa[t] = ld8(&lA[buf][ra * 32 + (quad ^ fsw) * 8]);
      int rb = wn + t * 16 + l16;
      fb[t] = ld8(&lB[buf][rb * 32 + (quad ^ fsw) * 8]);
    }
#pragma unroll
    for (int mt = 0; mt < 4; ++mt)
#pragma unroll
      for (int nt = 0; nt < 4; ++nt)
        acc[mt][nt] = mfma16(fa[mt], fb[nt], acc[mt][nt]);
  }

  // epilogue: C/D layout row=quad*4+r, col=l16
#pragma unroll
  for (int nt = 0; nt < 4; ++nt) {
    int ng = n0 + wn + nt * 16 + l16;
    int z = ng >> 9, col = ng & 511;
#pragma unroll
    for (int mt = 0; mt < 4; ++mt) {
#pragma unroll
      for (int r = 0; r < 4; ++r) {
        int m = m0 + wm + mt * 16 + quad * 4 + r;
        u16 h = f2bf(acc[mt][nt][r]);
        if (z == 0) qb[(size_t)m * SD + col] = h;
        else if (z == 1) kk[(size_t)m * SD + col] = h;
        else {
          int bb = m >> 11, t = m & 2047;
          vt[((size_t)bb * SD + col) * ST + t] = h;
        }
      }
    }
  }
}

// ---- Flash attention + LN: block = 64 q-rows (4 waves x 16), K/V chunks of 32 s
// staged in LDS via global_load_lds, double-buffered, one barrier per chunk.
__global__ __launch_bounds__(256, 1) void attn3(
    const u16* __restrict__ qb, const u16* __restrict__ kk,
    const u16* __restrict__ vt, const float* __restrict__ gamma,
    const float* __restrict__ beta, float* __restrict__ out) {
  __shared__ __align__(16) u16 lK[2][32 * 512];   // [s][d]
  __shared__ __align__(16) u16 lV[2][512 * 32];   // [d][s]
  __shared__ __align__(16) u16 plds[4][16 * 40];  // per-wave P, stride 40 (80 B)
  int tid = threadIdx.x;
  int wave = tid >> 6, lane = tid & 63;
  int quad = lane >> 4, l16 = lane & 15;
  int b = blockIdx.x & 7;                 // XCD/L2 locality
  int tt = 31 - (blockIdx.x >> 3);        // heavy tiles first
  int t0 = tt * 64;
  int t0w = t0 + wave * 16;
  int smaxw = t0w + 15;
  int nchunk = 2 * tt + 2;
  const float scale = 0.044194173824159216f;  // 512^-0.5
  const u16* kb0 = kk + (size_t)b * ST * SD;
  const u16* vb0 = vt + (size_t)b * SD * ST;
  u16* myp = &plds[wave][0];
  int srow = lane >> 2, schunk = lane & 3;
  int ksw = l16 & 7;          // K frag-read swizzle (s-row & 7)
  int vsw = (l16 >> 1) & 3;   // V frag-read swizzle ((d>>1)&3)

#define ATTN_STAGE(CH)                                                         \
  {                                                                            \
    int _buf = (CH)&1;                                                         \
    int _s0 = (CH)*32;                                                         \
    _Pragma("unroll") for (int i = 0; i < 8; ++i) {                            \
      int r = i * 4 + wave;                                                    \
      gl2lds(kb0 + (size_t)(_s0 + r) * SD + ((lane ^ (r & 7)) * 8),            \
             &lK[_buf][r * 512]);                                              \
    }                                                                          \
    _Pragma("unroll") for (int i = 0; i < 8; ++i) {                            \
      int d0 = (i * 4 + wave) * 16;                                            \
      int d = d0 + srow;                                                       \
      gl2lds(vb0 + (size_t)d * ST + _s0 + ((schunk ^ ((srow >> 1) & 3)) * 8),  \
             &lV[_buf][d0 * 32]);                                              \
    }                                                                          \
  }

  ATTN_STAGE(0);

  const u16* qp = qb + (size_t)(b * ST + t0w + l16) * SD + quad * 8;
  bf16x8 qf[16];
#pragma unroll
  for (int c = 0; c < 16; ++c) qf[c] = ld8(qp + c * 32);

  floatx4 zero = {0.f, 0.f, 0.f, 0.f};
  floatx4 acc[32];
#pragma unroll
  for (int i = 0; i < 32; ++i) acc[i] = zero;
  float mrow[4] = {-1e30f, -1e30f, -1e30f, -1e30f};
  float lrow[4] = {0.f, 0.f, 0.f, 0.f};

#pragma unroll 1
  for (int ch = 0; ch < nchunk; ++ch) {
    __syncthreads();  // chunk ch staged (vmcnt drain); buffer (ch+1)&1 free
    if (ch + 1 < nchunk) ATTN_STAGE(ch + 1);
    int s0 = ch * 32;
    if (s0 > smaxw) continue;  // fully-masked for this wave's rows
    int buf = ch & 1;
    const u16* lKb = &lK[buf][0];
    const u16* lVb = &lV[buf][0];
    bool diag = (s0 + 31) > t0w;

    floatx4 sacc[2] = {zero, zero};
#pragma unroll
    for (int c = 0; c < 16; ++c) {
      bf16x8 a = qf[c];
#pragma unroll
      for (int nt = 0; nt < 2; ++nt) {
        int sr = nt * 16 + l16;
        bf16x8 fb = ld8(lKb + sr * 512 + (((c * 4 + quad) ^ ksw) * 8));
        sacc[nt] = mfma16(a, fb, sacc[nt]);
      }
    }
#pragma unroll
    for (int nt = 0; nt < 2; ++nt) {
#pragma unroll
      for (int r = 0; r < 4; ++r) {
        float sv = sacc[nt][r] * scale;
        if (diag) {
          int sg = s0 + nt * 16 + l16;
          int tg = t0w + quad * 4 + r;
          sv = (sg > tg) ? -1e30f : sv;
        }
        sacc[nt][r] = sv;
      }
    }
    float mnew[4], alpha[4];
#pragma unroll
    for (int r = 0; r < 4; ++r) {
      float mx = fmaxf(sacc[0][r], sacc[1][r]);
      mx = fmaxf(mx, __shfl_xor(mx, 1));
      mx = fmaxf(mx, __shfl_xor(mx, 2));
      mx = fmaxf(mx, __shfl_xor(mx, 4));
      mx = fmaxf(mx, __shfl_xor(mx, 8));
      float mn = fmaxf(mrow[r], mx);
      alpha[r] = __expf(mrow[r] - mn);
      mnew[r] = mn;
      mrow[r] = mn;
    }
#pragma unroll
    for (int r = 0; r < 4; ++r) {
      float rs = 0.f;
#pragma unroll
      for (int nt = 0; nt < 2; ++nt) {
        float p = __expf(sacc[nt][r] - mnew[r]);  // masked -> exactly 0
        rs += p;
        myp[(quad * 4 + r) * 40 + nt * 16 + l16] = f2bf(p);
      }
      rs += __shfl_xor(rs, 1);
      rs += __shfl_xor(rs, 2);
      rs += __shfl_xor(rs, 4);
      rs += __shfl_xor(rs, 8);
      lrow[r] = lrow[r] * alpha[r] + rs;
    }
#pragma unroll
    for (int nt = 0; nt < 32; ++nt)
#pragma unroll
      for (int r = 0; r < 4; ++r) acc[nt][r] *= alpha[r];
    // P C-layout -> A-layout via private LDS (wave-local, no barrier)
    bf16x8 pf = ld8(myp + l16 * 40 + quad * 8);
#pragma unroll
    for (int nt = 0; nt < 32; ++nt) {
      int dr = nt * 16 + l16;
      bf16x8 vf = ld8(lVb + dr * 32 + ((quad ^ vsw) * 8));
      acc[nt] = mfma16(pf, vf, acc[nt]);
    }
  }

  // epilogue: O = acc/l, LayerNorm over D=512, f32 out
#pragma unroll
  for (int r = 0; r < 4; ++r) {
    float invl = 1.0f / lrow[r];
    float s1 = 0.f, s2 = 0.f;
#pragma unroll
    for (int nt = 0; nt < 32; ++nt) {
      float o = acc[nt][r] * invl;
      s1 += o;
      s2 += o * o;
    }
    s1 += __shfl_xor(s1, 1); s1 += __shfl_xor(s1, 2);
    s1 += __shfl_xor(s1, 4); s1 += __shfl_xor(s1, 8);
    s2 += __shfl_xor(s2, 1); s2 += __shfl_xor(s2, 2);
    s2 += __shfl_xor(s2, 4); s2 += __shfl_xor(s2, 8);
    float mu = s1 * (1.f / 512.f);
    float var = s2 * (1.f / 512.f) - mu * mu;
    float rstd = rsqrtf(var + 1e-5f);
    int t = t0w + quad * 4 + r;
    float* orow = out + (size_t)(b * ST + t) * SD;
#pragma unroll
    for (int nt = 0; nt < 32; ++nt) {
      int col = nt * 16 + l16;
      orow[col] = (acc[nt][r] * invl - mu) * rstd * gamma[col] + beta[col];
    }
  }
}

extern "C" void kernel_launch(void* const* d_in, const int* in_sizes, int n_in,
                              void* d_out, int out_size, void* d_ws, size_t ws_size,
                              hipStream_t stream) {
  (void)in_sizes; (void)n_in; (void)out_size; (void)ws_size;
  const float* x0 = (const float*)d_in[0];
  const float* x1 = (const float*)d_in[1];
  const float* Wq = (const float*)d_in[2];
  const float* Wk = (const float*)d_in[3];
  const float* Wv = (const float*)d_in[4];
  const float* gamma = (const float*)d_in[5];
  const float* beta = (const float*)d_in[6];
  u16* ws = (u16*)d_ws;
  u16* wt = ws;                                // 3*512*1024   ( 3.1 MB)
  u16* qb = wt + (size_t)3 * 512 * 1024;       // 16384*512    (16.8 MB)
  u16* kk = qb + (size_t)16384 * 512;          // 16384*512    (16.8 MB)
  u16* vt = kk + (size_t)16384 * 512;          // 8*512*2048   (16.8 MB)
  u16* xc = vt + (size_t)8 * 512 * 2048;       // 16384*1024   (33.6 MB)
  float* out = (float*)d_out;

  xcast<<<dim3(8192), dim3(256), 0, stream>>>(x0, x1, xc);
  wtrans<<<dim3(32, 16, 3), dim3(32, 8), 0, stream>>>(Wq, Wk, Wv, wt);
  qkv_m97<<<dim3(128, 12), dim3(256), 0, stream>>>(xc, wt, qb, kk, vt);
  attn3<<<dim3(256), dim3(256), 0, stream>>>(qb, kk, vt, gamma, beta, out);
}